// Round 1
// baseline (241.647 us; speedup 1.0000x reference)
//
#include <hip/hip_runtime.h>
#include <math.h>

#define N_NODES 4096
#define H 64
#define NE 24576
#define KNN 15

// ---------------- init: zero degree counters ----------------
__global__ void k_init(int* degR, int* degC) {
    int i = blockIdx.x * blockDim.x + threadIdx.x;
    if (i < N_NODES) { degR[i] = 0; degC[i] = 0; }
}

// ---------------- histogram of original edges ----------------
__global__ void k_hist(const int* __restrict__ edges, int* degR, int* degC) {
    int e = blockIdx.x * blockDim.x + threadIdx.x;
    if (e < NE) {
        atomicAdd(&degR[edges[e]], 1);
        atomicAdd(&degC[edges[NE + e]], 1);
    }
}

// ---------------- exclusive scan (one block) -> rowptr/colptr + cursors ----------------
__global__ __launch_bounds__(1024) void k_scan(const int* __restrict__ degR, const int* __restrict__ degC,
                                               int* rowptr, int* colptr, int* cursR, int* cursC) {
    __shared__ int buf[1024];
    int t = threadIdx.x;
    for (int which = 0; which < 2; ++which) {
        const int* deg = which ? degC : degR;
        int* ptr  = which ? colptr : rowptr;
        int* curs = which ? cursC : cursR;
        int base = t * 4;
        int v0 = deg[base], v1 = deg[base + 1], v2 = deg[base + 2], v3 = deg[base + 3];
        int s = v0 + v1 + v2 + v3;
        buf[t] = s;
        __syncthreads();
        int acc = s;
        for (int o = 1; o < 1024; o <<= 1) {
            int other = (t >= o) ? buf[t - o] : 0;
            __syncthreads();
            acc += other;
            buf[t] = acc;
            __syncthreads();
        }
        int excl = acc - s;
        ptr[base]     = excl;
        ptr[base + 1] = excl + v0;
        ptr[base + 2] = excl + v0 + v1;
        ptr[base + 3] = excl + v0 + v1 + v2;
        curs[base]     = excl;
        curs[base + 1] = excl + v0;
        curs[base + 2] = excl + v0 + v1;
        curs[base + 3] = excl + v0 + v1 + v2;
        if (t == 1023) ptr[N_NODES] = acc;
        __syncthreads();
    }
}

// ---------------- scatter edge ids into CSR (by r) and CSC (by c) ----------------
__global__ void k_scatter(const int* __restrict__ edges, int* cursR, int* cursC, int* eidR, int* eidC) {
    int e = blockIdx.x * blockDim.x + threadIdx.x;
    if (e < NE) {
        int r = edges[e], c = edges[NE + e];
        int p = atomicAdd(&cursR[r], 1); eidR[p] = e;
        int q = atomicAdd(&cursC[c], 1); eidC[q] = e;
    }
}

// ---------------- kNN: 1 wave per node, per-lane register top-15 + LDS merge ----------------
__global__ __launch_bounds__(64) void k_knn(const float* __restrict__ x, int* __restrict__ knn_idx) {
    int i = blockIdx.x;
    int lane = threadIdx.x;
    float xi0 = x[i * 3 + 0], xi1 = x[i * 3 + 1], xi2 = x[i * 3 + 2];
    float sqi = xi0 * xi0 + xi1 * xi1 + xi2 * xi2;

    float dlist[KNN]; int ilist[KNN];
#pragma unroll
    for (int t = 0; t < KNN; ++t) { dlist[t] = INFINITY; ilist[t] = -1; }

    for (int j = lane; j < N_NODES; j += 64) {
        if (j == i) continue;
        float y0 = x[j * 3 + 0], y1 = x[j * 3 + 1], y2 = x[j * 3 + 2];
        float sqj = y0 * y0 + y1 * y1 + y2 * y2;
        float dot = xi0 * y0 + xi1 * y1 + xi2 * y2;
        float d = sqi + sqj - 2.0f * dot;
        if (d < dlist[KNN - 1]) {
            dlist[KNN - 1] = d; ilist[KNN - 1] = j;
#pragma unroll
            for (int t = KNN - 1; t > 0; --t) {
                if (dlist[t] < dlist[t - 1]) {
                    float td = dlist[t]; dlist[t] = dlist[t - 1]; dlist[t - 1] = td;
                    int ti = ilist[t]; ilist[t] = ilist[t - 1]; ilist[t - 1] = ti;
                }
            }
        }
    }

    __shared__ float ld[64 * KNN];
    __shared__ int   li[64 * KNN];
#pragma unroll
    for (int t = 0; t < KNN; ++t) { ld[lane * KNN + t] = dlist[t]; li[lane * KNN + t] = ilist[t]; }
    __syncthreads();

    for (int r = 0; r < KNN; ++r) {
        float bd = INFINITY; int bs = -1;
#pragma unroll
        for (int t = 0; t < KNN; ++t) {
            int s = lane + 64 * t;
            float v = ld[s];
            if (v < bd) { bd = v; bs = s; }
        }
#pragma unroll
        for (int o = 32; o > 0; o >>= 1) {
            float od = __shfl_xor(bd, o);
            int   os = __shfl_xor(bs, o);
            if (od < bd) { bd = od; bs = os; }
        }
        bs = __shfl(bs, 0);  // consistent winner
        if (lane == 0) {
            knn_idx[i * KNN + r] = li[bs];
            ld[bs] = INFINITY;
        }
        __syncthreads();
    }
}

// ---------------- DevConv: gather-based segment max (deterministic, no atomics) ----------------
__global__ __launch_bounds__(64) void k_agg(const float* __restrict__ x, const int* __restrict__ edges,
                                            const int* __restrict__ rowptr, const int* __restrict__ eidR,
                                            const int* __restrict__ knn_idx, const float* __restrict__ Wt,
                                            float* __restrict__ agg) {
    int i = blockIdx.x;
    int h = threadIdx.x;
    float w0 = Wt[h * 3 + 0], w1 = Wt[h * 3 + 1], w2 = Wt[h * 3 + 2];
    float xi0 = x[i * 3], xi1 = x[i * 3 + 1], xi2 = x[i * 3 + 2];
    float m = -INFINITY;
    int s0 = rowptr[i], s1 = rowptr[i + 1];
    for (int s = s0; s < s1; ++s) {
        int e = eidR[s];
        int c = edges[NE + e];
        float d0 = x[c * 3] - xi0, d1 = x[c * 3 + 1] - xi1, d2 = x[c * 3 + 2] - xi2;
        float v = w0 * d0 + w1 * d1 + w2 * d2;
        m = fmaxf(m, v);
    }
    for (int t = 0; t < KNN; ++t) {
        int c = knn_idx[i * KNN + t];
        float d0 = x[c * 3] - xi0, d1 = x[c * 3 + 1] - xi1, d2 = x[c * 3 + 2] - xi2;
        float v = w0 * d0 + w1 * d1 + w2 * d2;
        m = fmaxf(m, v);
    }
    if (!(m > -INFINITY)) m = 0.0f;  // matches where(isfinite, agg, 0)
    agg[i * H + h] = m;
}

// ---------------- feat = agg@Wp.T ; q = feat@Wq.T ; k = feat@Wk.T (fused per row) ----------------
__global__ __launch_bounds__(64) void k_feat_qk(const float* __restrict__ agg, const float* __restrict__ Wp,
                                                const float* __restrict__ Wq, const float* __restrict__ Wk,
                                                float* __restrict__ qb, float* __restrict__ kb) {
    int i = blockIdx.x; int h = threadIdx.x;
    __shared__ float arow[H];
    __shared__ float frow[H];
    arow[h] = agg[i * H + h];
    __syncthreads();
    float f = 0.f;
    for (int k2 = 0; k2 < H; ++k2) f += Wp[h * H + k2] * arow[k2];
    frow[h] = f;
    __syncthreads();
    float qv = 0.f, kv = 0.f;
    for (int k2 = 0; k2 < H; ++k2) {
        float fr = frow[k2];
        qv += Wq[h * H + k2] * fr;
        kv += Wk[h * H + k2] * fr;
    }
    qb[i * H + h] = qv;
    kb[i * H + h] = kv;
}

// ---------------- attention scores: 1 wave per original edge ----------------
__global__ __launch_bounds__(256) void k_att(const int* __restrict__ edges, const float* __restrict__ qb,
                                             const float* __restrict__ kb, float* __restrict__ att) {
    int wid = (blockIdx.x * blockDim.x + threadIdx.x) >> 6;
    int lane = threadIdx.x & 63;
    if (wid >= NE) return;
    int r = edges[wid], c = edges[NE + wid];
    float v = qb[r * H + lane] * kb[c * H + lane];
#pragma unroll
    for (int o = 32; o > 0; o >>= 1) v += __shfl_xor(v, o);
    if (lane == 0) att[wid] = v;
}

// ---------------- segment softmax: 1 thread per node ----------------
__global__ void k_softmax(const int* __restrict__ rowptr, const int* __restrict__ eidR,
                          const float* __restrict__ att, float* __restrict__ attn) {
    int i = blockIdx.x * blockDim.x + threadIdx.x;
    if (i >= N_NODES) return;
    int s0 = rowptr[i], s1 = rowptr[i + 1];
    float m = -INFINITY;
    for (int s = s0; s < s1; ++s) m = fmaxf(m, att[eidR[s]]);
    float den = 0.f;
    for (int s = s0; s < s1; ++s) den += expf(att[eidR[s]] - m);
    for (int s = s0; s < s1; ++s) { int e = eidR[s]; attn[e] = expf(att[e] - m) / den; }
}

// ---------------- final: out[r,:] = (S@A@S^T)[r,:] with dense LDS rows ----------------
__global__ __launch_bounds__(256) void k_final(const int* __restrict__ edges,
                                               const int* __restrict__ rowptr, const int* __restrict__ eidR,
                                               const int* __restrict__ colptr, const int* __restrict__ eidC,
                                               const float* __restrict__ attn, float* __restrict__ out) {
    __shared__ __align__(16) float Trow[N_NODES];
    __shared__ __align__(16) float Orow[N_NODES];
    int r = blockIdx.x;
    int tid = threadIdx.x;
    for (int j = tid; j < N_NODES; j += 256) { Trow[j] = 0.f; Orow[j] = 0.f; }
    __syncthreads();

    // T[r, c2] = sum over S-edges (r,c) x A-edges (c,c2)
    int s0 = rowptr[r], s1 = rowptr[r + 1];
    for (int s = s0; s < s1; ++s) {
        int e = eidR[s];
        float sv = attn[e];
        int c = edges[NE + e];
        int a0 = rowptr[c], a1 = rowptr[c + 1];
        for (int a = a0 + tid; a < a1; a += 256) {
            int e2 = eidR[a];
            int c2 = edges[NE + e2];
            atomicAdd(&Trow[c2], sv);
        }
    }
    __syncthreads();

    // out[r, j] = sum_c2 T[r,c2] * S[j,c2]  (S columns via CSC)
    for (int c2 = tid; c2 < N_NODES; c2 += 256) {
        float t = Trow[c2];
        if (t != 0.f) {
            int b0 = colptr[c2], b1 = colptr[c2 + 1];
            for (int b = b0; b < b1; ++b) {
                int e = eidC[b];
                int j = edges[e];
                atomicAdd(&Orow[j], t * attn[e]);
            }
        }
    }
    __syncthreads();

    float4* o4 = (float4*)(out + (size_t)r * N_NODES);
    const float4* s4 = (const float4*)Orow;
    for (int j = tid; j < N_NODES / 4; j += 256) o4[j] = s4[j];
}

extern "C" void kernel_launch(void* const* d_in, const int* in_sizes, int n_in,
                              void* d_out, int out_size, void* d_ws, size_t ws_size,
                              hipStream_t stream) {
    const float* x    = (const float*)d_in[0];
    const int* edges  = (const int*)d_in[1];
    const float* Wt   = (const float*)d_in[2];
    const float* Wp   = (const float*)d_in[3];
    const float* Wq   = (const float*)d_in[4];
    const float* Wk   = (const float*)d_in[5];
    float* out = (float*)d_out;

    char* w = (char*)d_ws;
    size_t off = 0;
    auto alloc = [&](size_t bytes) -> void* {
        void* p = w + off;
        off += (bytes + 255) & ~(size_t)255;
        return p;
    };
    int*   knn    = (int*)  alloc((size_t)N_NODES * KNN * 4);
    float* agg    = (float*)alloc((size_t)N_NODES * H * 4);
    float* qb     = (float*)alloc((size_t)N_NODES * H * 4);
    float* kb     = (float*)alloc((size_t)N_NODES * H * 4);
    float* att    = (float*)alloc((size_t)NE * 4);
    float* attn   = (float*)alloc((size_t)NE * 4);
    int*   degR   = (int*)  alloc((size_t)N_NODES * 4);
    int*   degC   = (int*)  alloc((size_t)N_NODES * 4);
    int*   rowptr = (int*)  alloc((size_t)(N_NODES + 1) * 4);
    int*   colptr = (int*)  alloc((size_t)(N_NODES + 1) * 4);
    int*   cursR  = (int*)  alloc((size_t)N_NODES * 4);
    int*   cursC  = (int*)  alloc((size_t)N_NODES * 4);
    int*   eidR   = (int*)  alloc((size_t)NE * 4);
    int*   eidC   = (int*)  alloc((size_t)NE * 4);

    k_init<<<(N_NODES + 255) / 256, 256, 0, stream>>>(degR, degC);
    k_hist<<<(NE + 255) / 256, 256, 0, stream>>>(edges, degR, degC);
    k_knn<<<N_NODES, 64, 0, stream>>>(x, knn);
    k_scan<<<1, 1024, 0, stream>>>(degR, degC, rowptr, colptr, cursR, cursC);
    k_scatter<<<(NE + 255) / 256, 256, 0, stream>>>(edges, cursR, cursC, eidR, eidC);
    k_agg<<<N_NODES, 64, 0, stream>>>(x, edges, rowptr, eidR, knn, Wt, agg);
    k_feat_qk<<<N_NODES, 64, 0, stream>>>(agg, Wp, Wq, Wk, qb, kb);
    k_att<<<(NE * 64) / 256, 256, 0, stream>>>(edges, qb, kb, att);
    k_softmax<<<(N_NODES + 255) / 256, 256, 0, stream>>>(rowptr, eidR, att, attn);
    k_final<<<N_NODES, 256, 0, stream>>>(edges, rowptr, eidR, colptr, eidC, attn, out);
}